// Round 2
// baseline (12990.817 us; speedup 1.0000x reference)
//
#include <hip/hip_runtime.h>
#include <math.h>

// GraphODE (GCN + RK4 ODE block) on MI355X, fp32.
// Round 2: latency-optimized gathers (8-deep chunked, scalarized CSR bounds)
// and full fusion: SpMM + stage-GEMM + RK4 epilogue in one kernel (double-
// buffered hn), final SpMM + W2-GEMM + log_softmax in one kernel.

constexpr int kN = 100000;   // nodes
constexpr int kE = 1600000;  // edges
constexpr int kNPAD = 100352;
constexpr float kDT = 0.25f;
constexpr float kEPS = 1e-5f;

__device__ __forceinline__ float4 ld4(const float* p) { return *(const float4*)p; }

// ---------------- CSR build ----------------
__global__ void k_zero(int* cnt) {
  int i = blockIdx.x * 256 + threadIdx.x;
  if (i < kN) cnt[i] = 0;
}

__global__ void k_hist(const int* __restrict__ tgt, int* __restrict__ cnt) {
  int e = blockIdx.x * 256 + threadIdx.x;
  if (e < kE) atomicAdd(&cnt[tgt[e]], 1);
}

__global__ __launch_bounds__(256) void k_scan_a(const int* __restrict__ cnt,
                                                int* __restrict__ ptr,
                                                int* __restrict__ bsum) {
  int tid = threadIdx.x;
  int base = blockIdx.x * 1024;
  int i0 = base + tid * 4;
  int v[4];
#pragma unroll
  for (int t = 0; t < 4; ++t) v[t] = (i0 + t < kN) ? cnt[i0 + t] : 0;
  int ts = v[0] + v[1] + v[2] + v[3];
  int lane = tid & 63;
  int x = ts;
#pragma unroll
  for (int off = 1; off < 64; off <<= 1) {
    int y = __shfl_up(x, off);
    if (lane >= off) x += y;
  }
  __shared__ int wsum[4];
  if (lane == 63) wsum[tid >> 6] = x;
  __syncthreads();
  int woff = 0;
#pragma unroll
  for (int w = 0; w < 4; ++w)
    if (w < (tid >> 6)) woff += wsum[w];
  int o = woff + (x - ts);
#pragma unroll
  for (int t = 0; t < 4; ++t) {
    if (i0 + t < kN) ptr[i0 + t] = o;
    o += v[t];
  }
  if (tid == 255) bsum[blockIdx.x] = woff + x;
}

__global__ void k_scan_b(int* bsum, int nb) {
  int lane = threadIdx.x;  // blockDim = 64
  int carry = 0;
  for (int b = 0; b < nb; b += 64) {
    int i = b + lane;
    int v = (i < nb) ? bsum[i] : 0;
    int x = v;
#pragma unroll
    for (int off = 1; off < 64; off <<= 1) {
      int y = __shfl_up(x, off);
      if (lane >= off) x += y;
    }
    if (i < nb) bsum[i] = carry + x - v;
    carry += __shfl(x, 63);
  }
}

__global__ void k_scan_c(const int* __restrict__ bsum, int* __restrict__ ptr,
                         int* __restrict__ runp) {
  int i = blockIdx.x * 256 + threadIdx.x;
  if (i < kN) {
    int v = ptr[i] + bsum[i >> 10];
    ptr[i] = v;
    runp[i] = v;
  }
  if (i == 0) ptr[kN] = kE;
}

__global__ void k_scatter(const int* __restrict__ src, const int* __restrict__ tgt,
                          const float* __restrict__ w, int* __restrict__ runp,
                          float2* __restrict__ meta) {
  int e = blockIdx.x * 256 + threadIdx.x;
  if (e < kE) {
    int t = tgt[e];
    int pos = atomicAdd(&runp[t], 1);
    meta[pos] = make_float2(__int_as_float(src[e]), w[e]);
  }
}

// ------------- chunked row gather: 8 independent loads in flight -----------
template <bool DSUM>
__device__ __forceinline__ float gather_row(const float2* __restrict__ meta,
                                            const float* __restrict__ S,
                                            int e0, int e1, int lane,
                                            float& dsum) {
  float acc = 0.f, ds = 0.f;
  int e = e0;
  for (; e + 8 <= e1; e += 8) {
    float2 m0 = meta[e + 0], m1 = meta[e + 1], m2 = meta[e + 2], m3 = meta[e + 3];
    float2 m4 = meta[e + 4], m5 = meta[e + 5], m6 = meta[e + 6], m7 = meta[e + 7];
    float v0 = S[(long)__float_as_int(m0.x) * 64 + lane];
    float v1 = S[(long)__float_as_int(m1.x) * 64 + lane];
    float v2 = S[(long)__float_as_int(m2.x) * 64 + lane];
    float v3 = S[(long)__float_as_int(m3.x) * 64 + lane];
    float v4 = S[(long)__float_as_int(m4.x) * 64 + lane];
    float v5 = S[(long)__float_as_int(m5.x) * 64 + lane];
    float v6 = S[(long)__float_as_int(m6.x) * 64 + lane];
    float v7 = S[(long)__float_as_int(m7.x) * 64 + lane];
    acc += m0.y * v0; acc += m1.y * v1; acc += m2.y * v2; acc += m3.y * v3;
    acc += m4.y * v4; acc += m5.y * v5; acc += m6.y * v6; acc += m7.y * v7;
    if (DSUM) ds += m0.y + m1.y + m2.y + m3.y + m4.y + m5.y + m6.y + m7.y;
  }
  if (e + 4 <= e1) {
    float2 m0 = meta[e + 0], m1 = meta[e + 1], m2 = meta[e + 2], m3 = meta[e + 3];
    float v0 = S[(long)__float_as_int(m0.x) * 64 + lane];
    float v1 = S[(long)__float_as_int(m1.x) * 64 + lane];
    float v2 = S[(long)__float_as_int(m2.x) * 64 + lane];
    float v3 = S[(long)__float_as_int(m3.x) * 64 + lane];
    acc += m0.y * v0; acc += m1.y * v1; acc += m2.y * v2; acc += m3.y * v3;
    if (DSUM) ds += m0.y + m1.y + m2.y + m3.y;
    e += 4;
  }
  for (; e < e1; ++e) {
    float2 m = meta[e];
    acc += m.y * S[(long)__float_as_int(m.x) * 64 + lane];
    if (DSUM) ds += m.y;
  }
  if (DSUM) dsum = ds;
  return acc;
}

// ---------------- layer 0: h = relu(A@s), hn = gn(h), degw ----------------
__global__ __launch_bounds__(256) void k_layer0(
    const int* __restrict__ ptr, const float2* __restrict__ meta,
    const float* __restrict__ sbuf, const float* __restrict__ gn_w,
    const float* __restrict__ gn_b, float* __restrict__ h,
    float* __restrict__ hn_out, float* __restrict__ degw) {
  const int tid = threadIdx.x, lane = tid & 63;
  const int wv = (blockIdx.x << 2) + (tid >> 6);
  const float gw = gn_w[lane], gb = gn_b[lane];
  const int base = wv * 16;
  for (int u = 0; u < 16; ++u) {
    int n = base + u;
    if (n >= kN) return;
    int e0 = __builtin_amdgcn_readfirstlane(ptr[n]);
    int e1 = __builtin_amdgcn_readfirstlane(ptr[n + 1]);
    float dsum = 0.f;
    float acc = gather_row<true>(meta, sbuf, e0, e1, lane, dsum);
    long o = (long)n * 64 + lane;
    float hv = fmaxf(acc, 0.f);
    h[o] = hv;
    float d = 0.5f * (hv - __shfl_xor(hv, 1));
    float r = d * rsqrtf(d * d + kEPS);
    hn_out[o] = r * gw + gb;
    if (lane == 0) degw[n] = dsum;
  }
}

// ---------------- fused RK4 stage: gather + GEMM + epilogue ----------------
// z = A@hn_in ; k = relu(z@W1r + degw*(t*W1[0]+b1))
// INIT: kacc = k       else kacc += coef*k (not stored on IS3)
// IS3:  y = h + dt/6*kacc_new, h = y  else y = h + a_next*k
// hn_out = groupnorm(y)
template <int INIT, int IS3>
__global__ __launch_bounds__(256) void k_stage(
    const int* __restrict__ ptr, const float2* __restrict__ meta,
    const float* __restrict__ hn_in, const float* __restrict__ W1,
    const float* __restrict__ b1, const float* __restrict__ gn_w,
    const float* __restrict__ gn_b, const float* __restrict__ degw,
    float* __restrict__ h, float* __restrict__ kacc,
    float* __restrict__ hn_out, float t_s, float a_next, float coef) {
  __shared__ float Wl[64 * 64];
  const int tid = threadIdx.x;
  for (int i = tid * 4; i < 4096; i += 1024) *(float4*)&Wl[i] = ld4(W1 + 64 + i);
  __syncthreads();
  const int lane = tid & 63;
  const int wv = (blockIdx.x << 2) + (tid >> 6);
  const float bias_l = t_s * W1[lane] + b1[lane];
  const float gw = gn_w[lane], gb = gn_b[lane];
  const int base = wv * 16;
  float dum;
  for (int g = 0; g < 16; g += 8) {
    float z[8];
#pragma unroll
    for (int u = 0; u < 8; ++u) {
      int n = base + g + u;
      float zz = 0.f;
      if (n < kN) {
        int e0 = __builtin_amdgcn_readfirstlane(ptr[n]);
        int e1 = __builtin_amdgcn_readfirstlane(ptr[n + 1]);
        zz = gather_row<false>(meta, hn_in, e0, e1, lane, dum);
      }
      z[u] = zz;
    }
    float acc[8];
#pragma unroll
    for (int u = 0; u < 8; ++u) acc[u] = 0.f;
#pragma unroll
    for (int j = 0; j < 64; ++j) {
      float w = Wl[j * 64 + lane];
#pragma unroll
      for (int u = 0; u < 8; ++u) acc[u] += __shfl(z[u], j) * w;
    }
#pragma unroll
    for (int u = 0; u < 8; ++u) {
      int n = base + g + u;
      if (n < kN) {
        long o = (long)n * 64 + lane;
        float kv = fmaxf(acc[u] + degw[n] * bias_l, 0.f);
        float ka;
        if (INIT) ka = kv;
        else ka = kacc[o] + coef * kv;
        if (!IS3) kacc[o] = ka;
        float hv = h[o];
        float y;
        if (IS3) {
          y = hv + (kDT / 6.f) * ka;
          h[o] = y;
        } else {
          y = hv + a_next * kv;
        }
        float d = 0.5f * (y - __shfl_xor(y, 1));
        float r = d * rsqrtf(d * d + kEPS);
        hn_out[o] = r * gw + gb;
      }
    }
  }
}

// -------- final: gather A@h + W2-GEMM + degw*b2 + log_softmax --------------
__global__ __launch_bounds__(256) void k_fin(
    const int* __restrict__ ptr, const float2* __restrict__ meta,
    const float* __restrict__ hmat, const float* __restrict__ W2,
    const float* __restrict__ b2, const float* __restrict__ degw,
    float* __restrict__ out) {
  __shared__ float Wl[2624];  // 64x40 padded, zero-filled tail
  const int tid = threadIdx.x;
  for (int i = tid; i < 2624; i += 256) Wl[i] = (i < 2560) ? W2[i] : 0.f;
  __syncthreads();
  const int lane = tid & 63;
  const int wv = (blockIdx.x << 2) + (tid >> 6);
  const float b2l = (lane < 40) ? b2[lane] : 0.f;
  const int base = wv * 16;
  float dum;
  for (int g = 0; g < 16; g += 8) {
    float z[8];
#pragma unroll
    for (int u = 0; u < 8; ++u) {
      int n = base + g + u;
      float zz = 0.f;
      if (n < kN) {
        int e0 = __builtin_amdgcn_readfirstlane(ptr[n]);
        int e1 = __builtin_amdgcn_readfirstlane(ptr[n + 1]);
        zz = gather_row<false>(meta, hmat, e0, e1, lane, dum);
      }
      z[u] = zz;
    }
    float acc[8];
#pragma unroll
    for (int u = 0; u < 8; ++u) acc[u] = 0.f;
#pragma unroll
    for (int j = 0; j < 64; ++j) {
      float w = Wl[j * 40 + lane];
#pragma unroll
      for (int u = 0; u < 8; ++u) acc[u] += __shfl(z[u], j) * w;
    }
#pragma unroll
    for (int u = 0; u < 8; ++u) {
      int n = base + g + u;
      if (n < kN) {
        float a = acc[u] + degw[n] * b2l;
        float mv = (lane < 40) ? a : -INFINITY;
#pragma unroll
        for (int off = 32; off; off >>= 1) mv = fmaxf(mv, __shfl_xor(mv, off));
        float ev = (lane < 40) ? expf(a - mv) : 0.f;
#pragma unroll
        for (int off = 32; off; off >>= 1) ev += __shfl_xor(ev, off);
        float lse = logf(ev);
        if (lane < 40) out[(long)n * 40 + lane] = a - mv - lse;
      }
    }
  }
}

// ---------------- plain GEMM for layer-0 input: x@W0 (+b0) ----------------
template <int NCOL>
__global__ __launch_bounds__(256) void k_gemm64(const float* __restrict__ in,
                                                int in_stride,
                                                const float* __restrict__ W,
                                                const float* __restrict__ bias,
                                                float* __restrict__ out, int beta) {
  constexpr int NT = 128, ST = NT + 4, K = 64;
  __shared__ float Wl[K * 64];
  __shared__ float Zt[K * ST];
  const int tid = threadIdx.x;
  const int base = blockIdx.x * NT;
  for (int i = tid; i < K * 64; i += 256) {
    int j = i >> 6, c = i & 63;
    Wl[i] = (c < NCOL) ? W[j * NCOL + c] : 0.f;
  }
  for (int idx = tid; idx < (K / 4) * NT; idx += 256) {
    int node = idx & (NT - 1);
    int k4 = idx >> 7;
    int g = base + node;
    float4 v = make_float4(0.f, 0.f, 0.f, 0.f);
    if (g < kN) v = ld4(in + (long)g * in_stride + k4 * 4);
    int kk = k4 * 4;
    Zt[(kk + 0) * ST + node] = v.x;
    Zt[(kk + 1) * ST + node] = v.y;
    Zt[(kk + 2) * ST + node] = v.z;
    Zt[(kk + 3) * ST + node] = v.w;
  }
  __syncthreads();
  const int c0 = (tid & 15) * 4;
  const int n0 = (tid >> 4) * 8;
  float acc[8][4] = {};
#pragma unroll 8
  for (int j = 0; j < K; ++j) {
    float4 wv = ld4(Wl + j * 64 + c0);
    float4 za = ld4(Zt + j * ST + n0);
    float4 zb = ld4(Zt + j * ST + n0 + 4);
    float zv[8] = {za.x, za.y, za.z, za.w, zb.x, zb.y, zb.z, zb.w};
#pragma unroll
    for (int i = 0; i < 8; ++i) {
      acc[i][0] += zv[i] * wv.x;
      acc[i][1] += zv[i] * wv.y;
      acc[i][2] += zv[i] * wv.z;
      acc[i][3] += zv[i] * wv.w;
    }
  }
  if (c0 >= NCOL) return;
  float4 bv = make_float4(0.f, 0.f, 0.f, 0.f);
  if (bias) bv = ld4(bias + c0);
#pragma unroll
  for (int i = 0; i < 8; ++i) {
    int g = base + n0 + i;
    if (g >= kN) break;
    float* op = out + (long)g * NCOL + c0;
    float4 o = make_float4(acc[i][0] + bv.x, acc[i][1] + bv.y,
                           acc[i][2] + bv.z, acc[i][3] + bv.w);
    if (beta) {
      float4 p = ld4(op);
      o.x += p.x; o.y += p.y; o.z += p.z; o.w += p.w;
    }
    *(float4*)op = o;
  }
}

// ---------------- launch ----------------
extern "C" void kernel_launch(void* const* d_in, const int* in_sizes, int n_in,
                              void* d_out, int out_size, void* d_ws, size_t ws_size,
                              hipStream_t stream) {
  const float* x = (const float*)d_in[0];
  const int* src = (const int*)d_in[1];
  const int* tgt = (const int*)d_in[2];
  const float* mw = (const float*)d_in[3];
  const float* W0 = (const float*)d_in[4];
  const float* b0 = (const float*)d_in[5];
  const float* gnw = (const float*)d_in[6];
  const float* gnb = (const float*)d_in[7];
  const float* W1 = (const float*)d_in[8];
  const float* b1 = (const float*)d_in[9];
  const float* W2 = (const float*)d_in[10];
  const float* b2 = (const float*)d_in[11];
  float* out = (float*)d_out;

  // workspace carve-up
  int* cnt_run = (int*)d_ws;                 // kNPAD
  int* csr_ptr = cnt_run + kNPAD;            // kNPAD (need kN+1)
  int* bsum = csr_ptr + kNPAD;               // 128
  float2* meta = (float2*)(bsum + 128);      // kE
  float* degw = (float*)(meta + kE);         // kNPAD
  float* h = degw + kNPAD;                   // kN*64
  float* hnA = h + (long)kN * 64;
  float* hnB = hnA + (long)kN * 64;
  float* kacc = hnB + (long)kN * 64;         // doubles as layer-0 sbuf
  float* sbuf = kacc;

  // CSR build
  k_zero<<<391, 256, 0, stream>>>(cnt_run);
  k_hist<<<6250, 256, 0, stream>>>(tgt, cnt_run);
  k_scan_a<<<98, 256, 0, stream>>>(cnt_run, csr_ptr, bsum);
  k_scan_b<<<1, 64, 0, stream>>>(bsum, 98);
  k_scan_c<<<391, 256, 0, stream>>>(bsum, csr_ptr, cnt_run);
  k_scatter<<<6250, 256, 0, stream>>>(src, tgt, mw, cnt_run, meta);

  // layer 0 input transform: sbuf = x@W0 + b0 (two K=64 passes)
  k_gemm64<64><<<782, 256, 0, stream>>>(x, 128, W0, nullptr, sbuf, 0);
  k_gemm64<64><<<782, 256, 0, stream>>>(x + 64, 128, W0 + 64 * 64, b0, sbuf, 1);
  k_layer0<<<1563, 256, 0, stream>>>(csr_ptr, meta, sbuf, gnw, gnb, h, hnA, degw);

  // RK4 over t = 0, .25, .5, .75 ; hn ping-pongs A->B->A->B->A per step
  for (int step = 0; step < 4; ++step) {
    float t = step * kDT;
    k_stage<1, 0><<<1563, 256, 0, stream>>>(csr_ptr, meta, hnA, W1, b1, gnw, gnb,
                                            degw, h, kacc, hnB, t, 0.5f * kDT, 1.f);
    k_stage<0, 0><<<1563, 256, 0, stream>>>(csr_ptr, meta, hnB, W1, b1, gnw, gnb,
                                            degw, h, kacc, hnA, t + 0.5f * kDT,
                                            0.5f * kDT, 2.f);
    k_stage<0, 0><<<1563, 256, 0, stream>>>(csr_ptr, meta, hnA, W1, b1, gnw, gnb,
                                            degw, h, kacc, hnB, t + 0.5f * kDT,
                                            kDT, 2.f);
    k_stage<0, 1><<<1563, 256, 0, stream>>>(csr_ptr, meta, hnB, W1, b1, gnw, gnb,
                                            degw, h, kacc, hnA, t + kDT, 0.f, 1.f);
  }

  // final layer fused: out = log_softmax((A@h)@W2 + degw*b2)
  k_fin<<<1563, 256, 0, stream>>>(csr_ptr, meta, h, W2, b2, degw, out);
}

// Round 3
// 2034.064 us; speedup vs baseline: 6.3866x; 6.3866x over previous
//
#include <hip/hip_runtime.h>
#include <math.h>

// GraphODE (GCN + RK4 ODE block) on MI355X, fp32.
// Round 3: round-1 structure (separate lean SpMM + tiled stage-GEMM) with
// latency-optimized gathers: one node per wave, 8-deep independent row loads,
// scalarized CSR bounds + scalar (uniform) meta loads. No fat fusion (round-2
// fused kernel hit VGPR=256 -> spills -> occupancy collapse).

constexpr int kN = 100000;   // nodes
constexpr int kE = 1600000;  // edges
constexpr int kNPAD = 100352; // 98*1024
constexpr float kDT = 0.25f;
constexpr float kEPS = 1e-5f;

__device__ __forceinline__ float4 ld4(const float* p) { return *(const float4*)p; }
__device__ __forceinline__ void st4(float* p, float4 v) { *(float4*)p = v; }

// ---------------- CSR build ----------------
__global__ void k_zero(int* cnt) {
  int i = blockIdx.x * 256 + threadIdx.x;
  if (i < kN) cnt[i] = 0;
}

__global__ void k_hist(const int* __restrict__ tgt, int* __restrict__ cnt) {
  int e = blockIdx.x * 256 + threadIdx.x;
  if (e < kE) atomicAdd(&cnt[tgt[e]], 1);
}

__global__ __launch_bounds__(256) void k_scan_a(const int* __restrict__ cnt,
                                                int* __restrict__ ptr,
                                                int* __restrict__ bsum) {
  int tid = threadIdx.x;
  int base = blockIdx.x * 1024;
  int i0 = base + tid * 4;
  int v[4];
#pragma unroll
  for (int t = 0; t < 4; ++t) v[t] = (i0 + t < kN) ? cnt[i0 + t] : 0;
  int ts = v[0] + v[1] + v[2] + v[3];
  int lane = tid & 63;
  int x = ts;
#pragma unroll
  for (int off = 1; off < 64; off <<= 1) {
    int y = __shfl_up(x, off);
    if (lane >= off) x += y;
  }
  __shared__ int wsum[4];
  if (lane == 63) wsum[tid >> 6] = x;
  __syncthreads();
  int woff = 0;
#pragma unroll
  for (int w = 0; w < 4; ++w)
    if (w < (tid >> 6)) woff += wsum[w];
  int o = woff + (x - ts);  // exclusive within block
#pragma unroll
  for (int t = 0; t < 4; ++t) {
    if (i0 + t < kN) ptr[i0 + t] = o;
    o += v[t];
  }
  if (tid == 255) bsum[blockIdx.x] = woff + x;  // block total
}

__global__ void k_scan_b(int* bsum, int nb) {
  int lane = threadIdx.x;  // blockDim = 64
  int carry = 0;
  for (int b = 0; b < nb; b += 64) {
    int i = b + lane;
    int v = (i < nb) ? bsum[i] : 0;
    int x = v;
#pragma unroll
    for (int off = 1; off < 64; off <<= 1) {
      int y = __shfl_up(x, off);
      if (lane >= off) x += y;
    }
    if (i < nb) bsum[i] = carry + x - v;  // exclusive
    carry += __shfl(x, 63);
  }
}

__global__ void k_scan_c(const int* __restrict__ bsum, int* __restrict__ ptr,
                         int* __restrict__ runp) {
  int i = blockIdx.x * 256 + threadIdx.x;
  if (i < kN) {
    int v = ptr[i] + bsum[i >> 10];
    ptr[i] = v;
    runp[i] = v;
  }
  if (i == 0) ptr[kN] = kE;
}

__global__ void k_scatter(const int* __restrict__ src, const int* __restrict__ tgt,
                          const float* __restrict__ w, int* __restrict__ runp,
                          float2* __restrict__ meta) {
  int e = blockIdx.x * 256 + threadIdx.x;
  if (e < kE) {
    int t = tgt[e];
    int pos = atomicAdd(&runp[t], 1);
    meta[pos] = make_float2(__int_as_float(src[e]), w[e]);
  }
}

// ------------- chunked row gather: 8 independent loads in flight -----------
// e0/e1 are scalar (readfirstlane'd) so meta[e] loads are wave-uniform
// (scalar path); the 8 row gathers per chunk are independent vector loads.
template <bool DSUM>
__device__ __forceinline__ float gather_row(const float2* __restrict__ meta,
                                            const float* __restrict__ S,
                                            int e0, int e1, int lane,
                                            float& dsum) {
  float acc = 0.f, ds = 0.f;
  int e = e0;
  for (; e + 8 <= e1; e += 8) {
    float2 m0 = meta[e + 0], m1 = meta[e + 1], m2 = meta[e + 2], m3 = meta[e + 3];
    float2 m4 = meta[e + 4], m5 = meta[e + 5], m6 = meta[e + 6], m7 = meta[e + 7];
    float v0 = S[__float_as_int(m0.x) * 64 + lane];
    float v1 = S[__float_as_int(m1.x) * 64 + lane];
    float v2 = S[__float_as_int(m2.x) * 64 + lane];
    float v3 = S[__float_as_int(m3.x) * 64 + lane];
    float v4 = S[__float_as_int(m4.x) * 64 + lane];
    float v5 = S[__float_as_int(m5.x) * 64 + lane];
    float v6 = S[__float_as_int(m6.x) * 64 + lane];
    float v7 = S[__float_as_int(m7.x) * 64 + lane];
    acc += m0.y * v0; acc += m1.y * v1; acc += m2.y * v2; acc += m3.y * v3;
    acc += m4.y * v4; acc += m5.y * v5; acc += m6.y * v6; acc += m7.y * v7;
    if (DSUM) ds += m0.y + m1.y + m2.y + m3.y + m4.y + m5.y + m6.y + m7.y;
  }
  if (e + 4 <= e1) {
    float2 m0 = meta[e + 0], m1 = meta[e + 1], m2 = meta[e + 2], m3 = meta[e + 3];
    float v0 = S[__float_as_int(m0.x) * 64 + lane];
    float v1 = S[__float_as_int(m1.x) * 64 + lane];
    float v2 = S[__float_as_int(m2.x) * 64 + lane];
    float v3 = S[__float_as_int(m3.x) * 64 + lane];
    acc += m0.y * v0; acc += m1.y * v1; acc += m2.y * v2; acc += m3.y * v3;
    if (DSUM) ds += m0.y + m1.y + m2.y + m3.y;
    e += 4;
  }
  for (; e < e1; ++e) {
    float2 m = meta[e];
    acc += m.y * S[__float_as_int(m.x) * 64 + lane];
    if (DSUM) ds += m.y;
  }
  if (DSUM) dsum = ds;
  return acc;
}

// ---------------- SpMM: one node per wave, lane = feature ----------------
// LAYER0=1: h = relu(A@s), hn = gn(h), degw = row-sums.  LAYER0=0: z = A@hn.
template <int LAYER0>
__global__ __launch_bounds__(256) void k_spmm(
    const int* __restrict__ ptr, const float2* __restrict__ meta,
    const float* __restrict__ sbuf, float* __restrict__ zout,
    float* __restrict__ h, float* __restrict__ hn,
    const float* __restrict__ gn_w, const float* __restrict__ gn_b,
    float* __restrict__ degw) {
  int wid = (blockIdx.x * 256 + threadIdx.x) >> 6;
  int lane = threadIdx.x & 63;
  if (wid >= kN) return;
  int e0 = __builtin_amdgcn_readfirstlane(ptr[wid]);
  int e1 = __builtin_amdgcn_readfirstlane(ptr[wid + 1]);
  float dsum = 0.f;
  float acc = gather_row<LAYER0 != 0>(meta, sbuf, e0, e1, lane, dsum);
  long o = (long)wid * 64 + lane;
  if (LAYER0) {
    float hv = fmaxf(acc, 0.f);
    h[o] = hv;
    float d = 0.5f * (hv - __shfl_xor(hv, 1));  // group-size-2 GroupNorm
    float r = d * rsqrtf(d * d + kEPS);
    hn[o] = r * gn_w[lane] + gn_b[lane];
    if (lane == 0) degw[wid] = dsum;
  } else {
    zout[o] = acc;
  }
}

// ---------------- tiled stage GEMM + RK4 epilogue (round-1 proven) ---------
// k = relu(z@W1r + degw*(t*W1[0]+b1)); kacc init/+=coef*k;
// stage<3: y = h + a_next*k ; stage3: kacc+=k, y = h + dt/6*kacc, h=y.
// hn = groupnorm(y).
__global__ __launch_bounds__(256) void k_gemm_stage(
    const float* __restrict__ z, const float* __restrict__ W1,
    const float* __restrict__ b1, const float* __restrict__ gn_w,
    const float* __restrict__ gn_b, const float* __restrict__ degw,
    float* __restrict__ h, float* __restrict__ kacc, float* __restrict__ hn,
    float t_s, float a_next, float coef, int init_acc, int is_stage3) {
  constexpr int NT = 128, ST = NT + 4, K = 64;
  __shared__ float Wl[K * 64];
  __shared__ float Zt[K * ST];
  const int tid = threadIdx.x;
  const int base = blockIdx.x * NT;
  const float* Wr = W1 + 64;  // rows 1..64 of W1
  for (int i = tid; i < K * 64; i += 256) Wl[i] = Wr[i];
  for (int idx = tid; idx < (K / 4) * NT; idx += 256) {
    int node = idx & (NT - 1);
    int k4 = idx >> 7;
    int g = base + node;
    float4 v = make_float4(0.f, 0.f, 0.f, 0.f);
    if (g < kN) v = ld4(z + (long)g * 64 + k4 * 4);
    int kk = k4 * 4;
    Zt[(kk + 0) * ST + node] = v.x;
    Zt[(kk + 1) * ST + node] = v.y;
    Zt[(kk + 2) * ST + node] = v.z;
    Zt[(kk + 3) * ST + node] = v.w;
  }
  __syncthreads();
  const int c0 = (tid & 15) * 4;
  const int n0 = (tid >> 4) * 8;
  float acc[8][4] = {};
#pragma unroll 8
  for (int j = 0; j < K; ++j) {
    float4 wv = ld4(Wl + j * 64 + c0);
    float4 za = ld4(Zt + j * ST + n0);
    float4 zb = ld4(Zt + j * ST + n0 + 4);
    float zv[8] = {za.x, za.y, za.z, za.w, zb.x, zb.y, zb.z, zb.w};
#pragma unroll
    for (int i = 0; i < 8; ++i) {
      acc[i][0] += zv[i] * wv.x;
      acc[i][1] += zv[i] * wv.y;
      acc[i][2] += zv[i] * wv.z;
      acc[i][3] += zv[i] * wv.w;
    }
  }
  // per-column constants (node independent)
  float4 w0r = ld4(W1 + c0);
  float4 b1v = ld4(b1 + c0);
  float4 bias = make_float4(t_s * w0r.x + b1v.x, t_s * w0r.y + b1v.y,
                            t_s * w0r.z + b1v.z, t_s * w0r.w + b1v.w);
  float4 gw = ld4(gn_w + c0);
  float4 gb = ld4(gn_b + c0);
  const float c6 = kDT / 6.f;
#pragma unroll
  for (int i = 0; i < 8; ++i) {
    int g = base + n0 + i;
    if (g >= kN) break;
    float dg = degw[g];
    float4 kv = make_float4(fmaxf(acc[i][0] + dg * bias.x, 0.f),
                            fmaxf(acc[i][1] + dg * bias.y, 0.f),
                            fmaxf(acc[i][2] + dg * bias.z, 0.f),
                            fmaxf(acc[i][3] + dg * bias.w, 0.f));
    long o64 = (long)g * 64 + c0;
    float4 ka;
    if (init_acc) {
      ka = kv;
    } else {
      ka = ld4(kacc + o64);
      ka.x += coef * kv.x; ka.y += coef * kv.y;
      ka.z += coef * kv.z; ka.w += coef * kv.w;
    }
    if (!is_stage3) st4(kacc + o64, ka);
    float4 hv = ld4(h + o64);
    float4 y;
    if (is_stage3) {
      y = make_float4(hv.x + c6 * ka.x, hv.y + c6 * ka.y,
                      hv.z + c6 * ka.z, hv.w + c6 * ka.w);
      st4(h + o64, y);  // committed h for next RK4 step / final layer
    } else {
      y = make_float4(hv.x + a_next * kv.x, hv.y + a_next * kv.y,
                      hv.z + a_next * kv.z, hv.w + a_next * kv.w);
    }
    // GroupNorm, group size 2: pairs (x,y) and (z,w)
    float dx = 0.5f * (y.x - y.y);
    float rx = dx * rsqrtf(dx * dx + kEPS);
    float dz = 0.5f * (y.z - y.w);
    float rz = dz * rsqrtf(dz * dz + kEPS);
    float4 o = make_float4(rx * gw.x + gb.x, -rx * gw.y + gb.y,
                           rz * gw.z + gb.z, -rz * gw.w + gb.w);
    st4(hn + o64, o);
  }
}

// ---------------- final aggregate + log_softmax ----------------
__global__ __launch_bounds__(256) void k_final(const int* __restrict__ ptr,
                                               const float2* __restrict__ meta,
                                               const float* __restrict__ s2,
                                               float* __restrict__ out) {
  int wid = (blockIdx.x * 256 + threadIdx.x) >> 6;
  int lane = threadIdx.x & 63;
  if (wid >= kN) return;
  int e0 = __builtin_amdgcn_readfirstlane(ptr[wid]);
  int e1 = __builtin_amdgcn_readfirstlane(ptr[wid + 1]);
  float acc = 0.f;
  int e = e0;
  // 8-deep chunked gather over 40-col rows (lane>=40 contributes zeros)
  for (; e + 8 <= e1; e += 8) {
    float2 m0 = meta[e + 0], m1 = meta[e + 1], m2 = meta[e + 2], m3 = meta[e + 3];
    float2 m4 = meta[e + 4], m5 = meta[e + 5], m6 = meta[e + 6], m7 = meta[e + 7];
    if (lane < 40) {
      float v0 = s2[__float_as_int(m0.x) * 40 + lane];
      float v1 = s2[__float_as_int(m1.x) * 40 + lane];
      float v2 = s2[__float_as_int(m2.x) * 40 + lane];
      float v3 = s2[__float_as_int(m3.x) * 40 + lane];
      float v4 = s2[__float_as_int(m4.x) * 40 + lane];
      float v5 = s2[__float_as_int(m5.x) * 40 + lane];
      float v6 = s2[__float_as_int(m6.x) * 40 + lane];
      float v7 = s2[__float_as_int(m7.x) * 40 + lane];
      acc += m0.y * v0; acc += m1.y * v1; acc += m2.y * v2; acc += m3.y * v3;
      acc += m4.y * v4; acc += m5.y * v5; acc += m6.y * v6; acc += m7.y * v7;
    }
  }
  for (; e < e1; ++e) {
    float2 m = meta[e];
    if (lane < 40) acc += m.y * s2[__float_as_int(m.x) * 40 + lane];
  }
  float mv = (lane < 40) ? acc : -INFINITY;
#pragma unroll
  for (int off = 32; off; off >>= 1) mv = fmaxf(mv, __shfl_xor(mv, off));
  float ev = (lane < 40) ? expf(acc - mv) : 0.f;
#pragma unroll
  for (int off = 32; off; off >>= 1) ev += __shfl_xor(ev, off);
  float lse = logf(ev);
  if (lane < 40) out[(long)wid * 40 + lane] = acc - mv - lse;
}

// ---------------- plain GEMM: out = beta*out + in[:, :64]@W + bias ----------
template <int NCOL>
__global__ __launch_bounds__(256) void k_gemm64(const float* __restrict__ in,
                                                int in_stride,
                                                const float* __restrict__ W,
                                                const float* __restrict__ bias,
                                                float* __restrict__ out, int beta) {
  constexpr int NT = 128, ST = NT + 4, K = 64;
  __shared__ float Wl[K * 64];
  __shared__ float Zt[K * ST];
  const int tid = threadIdx.x;
  const int base = blockIdx.x * NT;
  for (int i = tid; i < K * 64; i += 256) {
    int j = i >> 6, c = i & 63;
    Wl[i] = (c < NCOL) ? W[j * NCOL + c] : 0.f;
  }
  for (int idx = tid; idx < (K / 4) * NT; idx += 256) {
    int node = idx & (NT - 1);
    int k4 = idx >> 7;
    int g = base + node;
    float4 v = make_float4(0.f, 0.f, 0.f, 0.f);
    if (g < kN) v = ld4(in + (long)g * in_stride + k4 * 4);
    int kk = k4 * 4;
    Zt[(kk + 0) * ST + node] = v.x;
    Zt[(kk + 1) * ST + node] = v.y;
    Zt[(kk + 2) * ST + node] = v.z;
    Zt[(kk + 3) * ST + node] = v.w;
  }
  __syncthreads();
  const int c0 = (tid & 15) * 4;
  const int n0 = (tid >> 4) * 8;
  float acc[8][4] = {};
#pragma unroll 8
  for (int j = 0; j < K; ++j) {
    float4 wv = ld4(Wl + j * 64 + c0);
    float4 za = ld4(Zt + j * ST + n0);
    float4 zb = ld4(Zt + j * ST + n0 + 4);
    float zv[8] = {za.x, za.y, za.z, za.w, zb.x, zb.y, zb.z, zb.w};
#pragma unroll
    for (int i = 0; i < 8; ++i) {
      acc[i][0] += zv[i] * wv.x;
      acc[i][1] += zv[i] * wv.y;
      acc[i][2] += zv[i] * wv.z;
      acc[i][3] += zv[i] * wv.w;
    }
  }
  if (c0 >= NCOL) return;
  float4 bv = make_float4(0.f, 0.f, 0.f, 0.f);
  if (bias) bv = ld4(bias + c0);
#pragma unroll
  for (int i = 0; i < 8; ++i) {
    int g = base + n0 + i;
    if (g >= kN) break;
    float* op = out + (long)g * NCOL + c0;
    float4 o = make_float4(acc[i][0] + bv.x, acc[i][1] + bv.y,
                           acc[i][2] + bv.z, acc[i][3] + bv.w);
    if (beta) {
      float4 p = ld4(op);
      o.x += p.x; o.y += p.y; o.z += p.z; o.w += p.w;
    }
    st4(op, o);
  }
}

// ---------------- launch ----------------
extern "C" void kernel_launch(void* const* d_in, const int* in_sizes, int n_in,
                              void* d_out, int out_size, void* d_ws, size_t ws_size,
                              hipStream_t stream) {
  const float* x = (const float*)d_in[0];
  const int* src = (const int*)d_in[1];
  const int* tgt = (const int*)d_in[2];
  const float* mw = (const float*)d_in[3];
  const float* W0 = (const float*)d_in[4];
  const float* b0 = (const float*)d_in[5];
  const float* gnw = (const float*)d_in[6];
  const float* gnb = (const float*)d_in[7];
  const float* W1 = (const float*)d_in[8];
  const float* b1 = (const float*)d_in[9];
  const float* W2 = (const float*)d_in[10];
  const float* b2 = (const float*)d_in[11];
  float* out = (float*)d_out;

  // workspace carve-up (round-1 layout)
  int* cnt_run = (int*)d_ws;                 // kNPAD ints
  int* csr_ptr = cnt_run + kNPAD;            // kNPAD ints (need kN+1)
  int* bsum = csr_ptr + kNPAD;               // 128 ints
  float2* meta = (float2*)(bsum + 128);      // kE float2
  float* degw = (float*)(meta + kE);         // kNPAD floats
  float* h = degw + kNPAD;                   // kN*64
  float* hn = h + (long)kN * 64;
  float* z = hn + (long)kN * 64;
  float* kacc = z + (long)kN * 64;

  // CSR build
  k_zero<<<391, 256, 0, stream>>>(cnt_run);
  k_hist<<<6250, 256, 0, stream>>>(tgt, cnt_run);
  k_scan_a<<<98, 256, 0, stream>>>(cnt_run, csr_ptr, bsum);
  k_scan_b<<<1, 64, 0, stream>>>(bsum, 98);
  k_scan_c<<<391, 256, 0, stream>>>(bsum, csr_ptr, cnt_run);
  k_scatter<<<6250, 256, 0, stream>>>(src, tgt, mw, cnt_run, meta);

  // layer 0: z = x@W0 + b0 (two K=64 passes), then h/hn/degw
  k_gemm64<64><<<782, 256, 0, stream>>>(x, 128, W0, nullptr, z, 0);
  k_gemm64<64><<<782, 256, 0, stream>>>(x + 64, 128, W0 + 64 * 64, b0, z, 1);
  k_spmm<1><<<25000, 256, 0, stream>>>(csr_ptr, meta, z, nullptr, h, hn, gnw, gnb, degw);

  // RK4 over t = 0, .25, .5, .75
  for (int step = 0; step < 4; ++step) {
    float t = step * kDT;
    const float ts[4] = {t, t + 0.5f * kDT, t + 0.5f * kDT, t + kDT};
    const float an[4] = {0.5f * kDT, 0.5f * kDT, kDT, 0.f};
    const float cf[4] = {1.f, 2.f, 2.f, 1.f};
    for (int s = 0; s < 4; ++s) {
      k_spmm<0><<<25000, 256, 0, stream>>>(csr_ptr, meta, hn, z, nullptr, nullptr,
                                           nullptr, nullptr, nullptr);
      k_gemm_stage<<<782, 256, 0, stream>>>(z, W1, b1, gnw, gnb, degw, h, kacc, hn,
                                            ts[s], an[s], cf[s],
                                            (s == 0) ? 1 : 0, (s == 3) ? 1 : 0);
    }
  }

  // final layer: s2 = h@W2 + b2 (into z), aggregate + log_softmax
  k_gemm64<40><<<782, 256, 0, stream>>>(h, 64, W2, b2, z, 0);
  k_final<<<25000, 256, 0, stream>>>(csr_ptr, meta, z, out);
}